// Round 6
// baseline (549.597 us; speedup 1.0000x reference)
//
#include <hip/hip_runtime.h>
#include <math.h>

#define N_NODES 50000
#define N_EDGES 800000
#define HD 128          // H*D = 4*32
#define GG 1024
#define NEG_SLOPE 0.2f
#define SCAN_B 1024
#define NB ((N_NODES + SCAN_B - 1) / SCAN_B)   // 49

typedef __attribute__((ext_vector_type(8))) short bf16x8;
typedef __attribute__((ext_vector_type(4))) float f32x4;

__device__ __forceinline__ unsigned short f2bf(float v) {
    unsigned u = __float_as_uint(v);
    u += 0x7fff + ((u >> 16) & 1);       // round-to-nearest-even
    return (unsigned short)(u >> 16);
}
__device__ __forceinline__ float bf2f(unsigned short s) {
    return __uint_as_float((unsigned)s << 16);
}

// --------------------------------------------------- split-bf16 conversions
__global__ void convert_x(const float* __restrict__ x, unsigned short* __restrict__ Xh,
                          unsigned short* __restrict__ Xl, int total)
{
    int i = blockIdx.x * 256 + threadIdx.x;
    if (i >= total) return;
    float v = x[i];
    unsigned short hi = f2bf(v);
    unsigned short lo = f2bf(v - bf2f(hi));   // residual exact in fp32
    Xh[i] = hi; Xl[i] = lo;
}

// all 3 layers' W pairs -> Wt[256][K] transposed split hi/lo, one dispatch.
// out layout: layer stride 256*128 elems; within layer: c*K + k.
__global__ void convert_w_all(const float* __restrict__ W0l, const float* __restrict__ W0r,
                              const float* __restrict__ W1l, const float* __restrict__ W1r,
                              const float* __restrict__ W2l, const float* __restrict__ W2r,
                              unsigned short* __restrict__ Wth, unsigned short* __restrict__ Wtl)
{
    int t = blockIdx.x * 256 + threadIdx.x;
    if (t >= 256 * 64 + 2 * 256 * 128) return;
    int l, local, K;
    const float* Wl; const float* Wr;
    if (t < 256 * 64)            { l = 0; local = t;              K = 64;  Wl = W0l; Wr = W0r; }
    else if (t < 256 * 64 + 256 * 128) { l = 1; local = t - 256 * 64;  K = 128; Wl = W1l; Wr = W1r; }
    else                         { l = 2; local = t - 256 * 64 - 256 * 128; K = 128; Wl = W2l; Wr = W2r; }
    int c = local / K, k = local - c * K;
    float v = (c < 128) ? Wl[(size_t)k * 128 + c] : Wr[(size_t)k * 128 + (c - 128)];
    unsigned short hi = f2bf(v);
    unsigned short lo = f2bf(v - bf2f(hi));
    Wth[l * 256 * 128 + local] = hi;
    Wtl[l * 256 * 128 + local] = lo;
}

// --------------------------------------------------- MFMA split-bf16 dual GEMM v3
// NO LDS, NO barriers. A-frags direct from global (L1: all 4 waves share the same
// 64 rows); B-frags direct from global (W = 128 KB, L2-resident for all blocks).
// Register double-buffer across K-chunks: load ch+1 while 48 MFMAs run on ch.
// Block: 64 rows x 256 cols (Wl||Wr), 4 waves, wave-tile 64x64.
template<int K>
__launch_bounds__(256)
__global__ void gemm_mfma(const unsigned short* __restrict__ Xh, const unsigned short* __restrict__ Xl,
                          const unsigned short* __restrict__ Wth, const unsigned short* __restrict__ Wtl,
                          const float* __restrict__ bl, const float* __restrict__ br,
                          float* __restrict__ Cl, float* __restrict__ Cr, int n)
{
    constexpr int NCH = K / 32;
    const int tid  = threadIdx.x;
    const int wave = tid >> 6;
    const int lane = tid & 63;
    const int quad = lane >> 4;
    const int l15  = lane & 15;
    const int row0 = blockIdx.x * 64;

    f32x4 acc[4][4];
    #pragma unroll
    for (int i = 0; i < 4; i++)
        #pragma unroll
        for (int j = 0; j < 4; j++) acc[i][j] = (f32x4){0.f, 0.f, 0.f, 0.f};

    // per-lane base offsets (rows clamped to n-1: reads stay in-buffer, results discarded)
    size_t aoff[4];
    #pragma unroll
    for (int mt = 0; mt < 4; mt++) {
        int r = row0 + mt * 16 + l15;
        if (r >= n) r = n - 1;
        aoff[mt] = (size_t)r * K + quad * 8;
    }
    size_t boff[4];
    #pragma unroll
    for (int nt = 0; nt < 4; nt++)
        boff[nt] = (size_t)(wave * 64 + nt * 16 + l15) * K + quad * 8;

    bf16x8 ah[4], al[4], bh[4], bo[4];
    #pragma unroll
    for (int mt = 0; mt < 4; mt++) {
        ah[mt] = *(const bf16x8*)(Xh + aoff[mt]);
        al[mt] = *(const bf16x8*)(Xl + aoff[mt]);
    }
    #pragma unroll
    for (int nt = 0; nt < 4; nt++) {
        bh[nt] = *(const bf16x8*)(Wth + boff[nt]);
        bo[nt] = *(const bf16x8*)(Wtl + boff[nt]);
    }

    #pragma unroll
    for (int ch = 1; ch <= NCH; ch++) {
        bf16x8 nah[4], nal[4], nbh[4], nbo[4];
        if (ch < NCH) {
            const int ko = ch * 32;
            #pragma unroll
            for (int mt = 0; mt < 4; mt++) {
                nah[mt] = *(const bf16x8*)(Xh + aoff[mt] + ko);
                nal[mt] = *(const bf16x8*)(Xl + aoff[mt] + ko);
            }
            #pragma unroll
            for (int nt = 0; nt < 4; nt++) {
                nbh[nt] = *(const bf16x8*)(Wth + boff[nt] + ko);
                nbo[nt] = *(const bf16x8*)(Wtl + boff[nt] + ko);
            }
        }
        #pragma unroll
        for (int nt = 0; nt < 4; nt++) {
            #pragma unroll
            for (int mt = 0; mt < 4; mt++) {
                acc[mt][nt] = __builtin_amdgcn_mfma_f32_16x16x32_bf16(ah[mt], bh[nt], acc[mt][nt], 0, 0, 0);
                acc[mt][nt] = __builtin_amdgcn_mfma_f32_16x16x32_bf16(ah[mt], bo[nt], acc[mt][nt], 0, 0, 0);
                acc[mt][nt] = __builtin_amdgcn_mfma_f32_16x16x32_bf16(al[mt], bh[nt], acc[mt][nt], 0, 0, 0);
            }
        }
        if (ch < NCH) {
            #pragma unroll
            for (int i = 0; i < 4; i++) {
                ah[i] = nah[i]; al[i] = nal[i];
                bh[i] = nbh[i]; bo[i] = nbo[i];
            }
        }
    }

    // epilogue: C/D layout col=lane&15, row=quad*4+reg
    const bool isL = (wave < 2);
    const int colbase = (wave & 1) * 64;
    const float* bias = isL ? bl : br;
    float* C = isL ? Cl : Cr;
    #pragma unroll
    for (int nt = 0; nt < 4; nt++) {
        const float bv = bias[colbase + nt * 16 + l15];
        #pragma unroll
        for (int mt = 0; mt < 4; mt++) {
            #pragma unroll
            for (int r = 0; r < 4; r++) {
                const int row = row0 + mt * 16 + quad * 4 + r;
                if (row < n)
                    C[(size_t)row * 128 + colbase + nt * 16 + l15] = acc[mt][nt][r] + bv;
            }
        }
    }
}

// ---------------------------------------------------------------- CSR build
__global__ void deg_hist(const int* __restrict__ dst, int* __restrict__ deg) {
    int e = blockIdx.x * 256 + threadIdx.x;
    if (e < N_EDGES) atomicAdd(&deg[dst[e]], 1);
}

__launch_bounds__(SCAN_B)
__global__ void scan_block(const int* __restrict__ deg, int* __restrict__ rowptr,
                           int* __restrict__ btot)
{
    __shared__ int s[SCAN_B];
    const int tid = threadIdx.x;
    const int i = blockIdx.x * SCAN_B + tid;
    int v = (i < N_NODES) ? deg[i] : 0;
    s[tid] = v;
    __syncthreads();
    for (int off = 1; off < SCAN_B; off <<= 1) {
        int t = (tid >= off) ? s[tid - off] : 0;
        __syncthreads();
        s[tid] += t;
        __syncthreads();
    }
    if (i < N_NODES) rowptr[i] = s[tid] - v;
    if (tid == SCAN_B - 1) btot[blockIdx.x] = s[SCAN_B - 1];
}

__global__ void scan_btot(const int* __restrict__ btot, int* __restrict__ boff) {
    if (threadIdx.x == 0) {
        int a = 0;
        for (int b = 0; b < NB; b++) { boff[b] = a; a += btot[b]; }
        boff[NB] = a;
    }
}

__global__ void scan_add(const int* __restrict__ boff, int* __restrict__ rowptr,
                         int* __restrict__ cursor)
{
    int i = blockIdx.x * 256 + threadIdx.x;
    if (i < N_NODES) {
        int r = rowptr[i] + boff[i >> 10];
        rowptr[i] = r;
        cursor[i] = r;
    }
    if (i == N_NODES) rowptr[N_NODES] = boff[NB];
}

__global__ void scatter_csr(const int* __restrict__ src, const int* __restrict__ dst,
                            int* __restrict__ cursor, int* __restrict__ csr_src)
{
    int e = blockIdx.x * 256 + threadIdx.x;
    if (e >= N_EDGES) return;
    int pos = atomicAdd(&cursor[dst[e]], 1);
    csr_src[pos] = src[e];
}

// graph boundaries from sorted batch: gptr[G+1]
__global__ void build_gptr(const int* __restrict__ batch, int* __restrict__ gptr) {
    int i = blockIdx.x * 256 + threadIdx.x;
    if (i > N_NODES) return;
    if (i == 0) {
        for (int g = 0; g <= batch[0]; g++) gptr[g] = 0;
    } else if (i == N_NODES) {
        for (int g = batch[N_NODES - 1] + 1; g <= GG; g++) gptr[g] = N_NODES;
    } else {
        int b0 = batch[i - 1], b1 = batch[i];
        for (int g = b0 + 1; g <= b1; g++) gptr[g] = i;
    }
}

// ------------------------------------------------- fused per-node attention
// one wave per dst node, FOUR edges in flight (16 lanes x 8 dims each),
// depth-2 software pipeline on the value gather.
__launch_bounds__(256)
__global__ void node_attn(const float* __restrict__ xl, const float* __restrict__ xr,
                          const int* __restrict__ rowptr, const int* __restrict__ csr_src,
                          const float* __restrict__ att, const float* __restrict__ bvec,
                          unsigned short* __restrict__ Hh, unsigned short* __restrict__ Hl)
{
    const int node = (blockIdx.x * 256 + threadIdx.x) >> 6;
    const int lane = threadIdx.x & 63;
    if (node >= N_NODES) return;
    const int eslot = lane >> 4;         // edge slot 0..3
    const int li    = lane & 15;         // dims li*8 .. li*8+7 (head = li>>2)

    const float* xrp = xr + (size_t)node * HD + li * 8;
    const float4 xr0 = *(const float4*)(xrp);
    const float4 xr1 = *(const float4*)(xrp + 4);
    const float4 aw0 = *(const float4*)(att + li * 8);
    const float4 aw1 = *(const float4*)(att + li * 8 + 4);
    const int beg = rowptr[node];
    const int end = rowptr[node + 1];

    float m = -1e30f, l = 0.f;
    float4 a0 = make_float4(0.f, 0.f, 0.f, 0.f);
    float4 a1 = make_float4(0.f, 0.f, 0.f, 0.f);

    // depth-2 pipeline: cur (c*), next (p*)
    int i0 = beg + eslot;
    int s0 = (i0 < end) ? csr_src[i0] : 0;
    const float* rp0 = xl + (size_t)s0 * HD + li * 8;
    float4 c0 = *(const float4*)(rp0);
    float4 c1 = *(const float4*)(rp0 + 4);
    int i1 = beg + 4 + eslot;
    int s1 = (i1 < end) ? csr_src[i1] : 0;
    const float* rp1 = xl + (size_t)s1 * HD + li * 8;
    float4 p0 = *(const float4*)(rp1);
    float4 p1 = *(const float4*)(rp1 + 4);

    for (int base = beg; base < end; base += 4) {
        const bool valid = (base + eslot) < end;
        // prefetch base+8 (2 iterations ahead)
        float4 r0 = p0, r1 = p1;
        if (base + 8 < end) {
            int e2 = base + 8 + eslot;
            int s2 = (e2 < end) ? csr_src[e2] : 0;
            const float* rp = xl + (size_t)s2 * HD + li * 8;
            r0 = *(const float4*)(rp);
            r1 = *(const float4*)(rp + 4);
        }
        // score partial over this lane's 8 dims: leaky = max(t, 0.2t)
        float t, p;
        t = c0.x + xr0.x; t = fmaxf(t, NEG_SLOPE * t); p  = t * aw0.x;
        t = c0.y + xr0.y; t = fmaxf(t, NEG_SLOPE * t); p += t * aw0.y;
        t = c0.z + xr0.z; t = fmaxf(t, NEG_SLOPE * t); p += t * aw0.z;
        t = c0.w + xr0.w; t = fmaxf(t, NEG_SLOPE * t); p += t * aw0.w;
        t = c1.x + xr1.x; t = fmaxf(t, NEG_SLOPE * t); p += t * aw1.x;
        t = c1.y + xr1.y; t = fmaxf(t, NEG_SLOPE * t); p += t * aw1.y;
        t = c1.z + xr1.z; t = fmaxf(t, NEG_SLOPE * t); p += t * aw1.z;
        t = c1.w + xr1.w; t = fmaxf(t, NEG_SLOPE * t); p += t * aw1.w;
        p += __shfl_xor(p, 1);
        p += __shfl_xor(p, 2);           // head score replicated in 4-lane group

        if (!__any(valid && (p > m))) {  // fast path: no head's max improves
            const float w = valid ? __expf(p - m) : 0.f;
            l += w;
            a0.x += w * c0.x; a0.y += w * c0.y; a0.z += w * c0.z; a0.w += w * c0.w;
            a1.x += w * c1.x; a1.y += w * c1.y; a1.z += w * c1.z; a1.w += w * c1.w;
        } else {
            const float mn = valid ? fmaxf(m, p) : m;
            const float sc = __expf(m - mn);
            const float w  = valid ? __expf(p - mn) : 0.f;
            l = l * sc + w;
            a0.x = a0.x * sc + w * c0.x; a0.y = a0.y * sc + w * c0.y;
            a0.z = a0.z * sc + w * c0.z; a0.w = a0.w * sc + w * c0.w;
            a1.x = a1.x * sc + w * c1.x; a1.y = a1.y * sc + w * c1.y;
            a1.z = a1.z * sc + w * c1.z; a1.w = a1.w * sc + w * c1.w;
            m = mn;
        }
        c0 = p0; c1 = p1; p0 = r0; p1 = r1;
    }

    // merge the 4 edge-slot softmax states (xor 16, then xor 32)
    #pragma unroll
    for (int off = 16; off <= 32; off <<= 1) {
        const float mo = __shfl_xor(m, off);
        const float lo = __shfl_xor(l, off);
        float4 b0, b1;
        b0.x = __shfl_xor(a0.x, off); b0.y = __shfl_xor(a0.y, off);
        b0.z = __shfl_xor(a0.z, off); b0.w = __shfl_xor(a0.w, off);
        b1.x = __shfl_xor(a1.x, off); b1.y = __shfl_xor(a1.y, off);
        b1.z = __shfl_xor(a1.z, off); b1.w = __shfl_xor(a1.w, off);
        const float mm = fmaxf(m, mo);
        const float e1 = __expf(m - mm);
        const float e2 = __expf(mo - mm);
        l = l * e1 + lo * e2;
        a0.x = a0.x * e1 + b0.x * e2; a0.y = a0.y * e1 + b0.y * e2;
        a0.z = a0.z * e1 + b0.z * e2; a0.w = a0.w * e1 + b0.w * e2;
        a1.x = a1.x * e1 + b1.x * e2; a1.y = a1.y * e1 + b1.y * e2;
        a1.z = a1.z * e1 + b1.z * e2; a1.w = a1.w * e1 + b1.w * e2;
        m = mm;
    }

    if (eslot == 0) {
        const float inv = (l > 0.f) ? 1.f / l : 0.f;
        const float4 bb0 = *(const float4*)(bvec + li * 8);
        const float4 bb1 = *(const float4*)(bvec + li * 8 + 4);
        float o[8];
        o[0] = a0.x * inv + bb0.x; o[1] = a0.y * inv + bb0.y;
        o[2] = a0.z * inv + bb0.z; o[3] = a0.w * inv + bb0.w;
        o[4] = a1.x * inv + bb1.x; o[5] = a1.y * inv + bb1.y;
        o[6] = a1.z * inv + bb1.z; o[7] = a1.w * inv + bb1.w;
        uint4 ph, pl;
        unsigned* php = (unsigned*)&ph;
        unsigned* plp = (unsigned*)&pl;
        #pragma unroll
        for (int j = 0; j < 4; j++) {
            float u0 = o[2*j], u1 = o[2*j+1];
            u0 = (u0 > 0.f) ? u0 : expm1f(u0);
            u1 = (u1 > 0.f) ? u1 : expm1f(u1);
            unsigned short h0 = f2bf(u0), h1 = f2bf(u1);
            unsigned short q0 = f2bf(u0 - bf2f(h0)), q1 = f2bf(u1 - bf2f(h1));
            php[j] = (unsigned)h0 | ((unsigned)h1 << 16);
            plp[j] = (unsigned)q0 | ((unsigned)q1 << 16);
        }
        *(uint4*)(Hh + (size_t)node * HD + li * 8) = ph;
        *(uint4*)(Hl + (size_t)node * HD + li * 8) = pl;
    }
}

// ------------------------------------------ fused mean-pool + linear head
__launch_bounds__(256)
__global__ void pool_head(const unsigned short* __restrict__ Hh, const unsigned short* __restrict__ Hl,
                          const int* __restrict__ gptr, const float* __restrict__ Wh,
                          const float* __restrict__ bh, float* __restrict__ out)
{
    const int g = (blockIdx.x * 256 + threadIdx.x) >> 6;
    const int lane = threadIdx.x & 63;
    if (g >= GG) return;
    const int b0 = gptr[g], b1 = gptr[g + 1];
    const float2 w = *(const float2*)(Wh + lane * 2);
    float sx = 0.f, sy = 0.f;
    for (int i = b0; i < b1; i++) {
        const unsigned vh = *(const unsigned*)(Hh + (size_t)i * HD + lane * 2);
        const unsigned vl = *(const unsigned*)(Hl + (size_t)i * HD + lane * 2);
        sx += bf2f((unsigned short)(vh & 0xffff)) + bf2f((unsigned short)(vl & 0xffff));
        sy += bf2f((unsigned short)(vh >> 16))    + bf2f((unsigned short)(vl >> 16));
    }
    float d = sx * w.x + sy * w.y;
    d += __shfl_xor(d, 1);
    d += __shfl_xor(d, 2);
    d += __shfl_xor(d, 4);
    d += __shfl_xor(d, 8);
    d += __shfl_xor(d, 16);
    d += __shfl_xor(d, 32);
    if (lane == 0) out[g] = d / fmaxf((float)(b1 - b0), 1.f) + bh[0];
}

// ---------------------------------------------------------------- launch
extern "C" void kernel_launch(void* const* d_in, const int* in_sizes, int n_in,
                              void* d_out, int out_size, void* d_ws, size_t ws_size,
                              hipStream_t stream)
{
    const float* x     = (const float*)d_in[0];
    const int*   edge  = (const int*)d_in[1];
    const int*   batch = (const int*)d_in[2];
    const int*   src   = edge;
    const int*   dst   = edge + N_EDGES;
    const float* Wh    = (const float*)d_in[21];
    const float* bh    = (const float*)d_in[22];
    float* out = (float*)d_out;

    const size_t N128 = (size_t)N_NODES * HD;
    float* buf_xl = (float*)d_ws;                       // N*128 f32
    float* buf_xr = buf_xl + N128;                      // N*128 f32
    unsigned short* Xh  = (unsigned short*)(buf_xr + N128);   // N*128 bf16
    unsigned short* Xl_ = Xh + N128;                    // N*128 bf16
    unsigned short* Wth = Xl_ + N128;                   // 3 * 256*128 bf16
    unsigned short* Wtl = Wth + 3 * 256 * 128;          // 3 * 256*128 bf16
    int* deg     = (int*)(Wtl + 3 * 256 * 128);         // N
    int* rowptr  = deg + N_NODES;                       // N+1
    int* cursor  = rowptr + N_NODES + 1;                // N
    int* csr_src = cursor + N_NODES;                    // E
    int* btot    = csr_src + N_EDGES;                   // NB
    int* boff    = btot + NB;                           // NB+1
    int* gptr    = boff + NB + 1;                       // G+1

    // ---- CSR + graph-boundary build (layer-invariant)
    hipMemsetAsync(deg, 0, (size_t)N_NODES * sizeof(int), stream);
    deg_hist<<<(N_EDGES + 255) / 256, 256, 0, stream>>>(dst, deg);
    scan_block<<<NB, SCAN_B, 0, stream>>>(deg, rowptr, btot);
    scan_btot<<<1, 64, 0, stream>>>(btot, boff);
    scan_add<<<(N_NODES + 256) / 256, 256, 0, stream>>>(boff, rowptr, cursor);
    scatter_csr<<<(N_EDGES + 255) / 256, 256, 0, stream>>>(src, dst, cursor, csr_src);
    build_gptr<<<(N_NODES + 256) / 256, 256, 0, stream>>>(batch, gptr);

    // ---- weight + layer-0 input split-bf16 conversion
    convert_x<<<(N_NODES * 64 + 255) / 256, 256, 0, stream>>>(x, Xh, Xl_, N_NODES * 64);
    convert_w_all<<<(256 * 64 + 2 * 256 * 128 + 255) / 256, 256, 0, stream>>>(
        (const float*)d_in[3],  (const float*)d_in[5],
        (const float*)d_in[9],  (const float*)d_in[11],
        (const float*)d_in[15], (const float*)d_in[17], Wth, Wtl);

    const int gemm_grid = (N_NODES + 63) / 64;
    const int attn_grid = (N_NODES + 3) / 4;

    for (int l = 0; l < 3; l++) {
        const float* bl  = (const float*)d_in[4 + 6 * l];
        const float* br  = (const float*)d_in[6 + 6 * l];
        const float* att = (const float*)d_in[7 + 6 * l];
        const float* bb  = (const float*)d_in[8 + 6 * l];

        if (l == 0)
            gemm_mfma<64><<<gemm_grid, 256, 0, stream>>>(Xh, Xl_, Wth, Wtl,
                                                         bl, br, buf_xl, buf_xr, N_NODES);
        else
            gemm_mfma<128><<<gemm_grid, 256, 0, stream>>>(Xh, Xl_,
                                                          Wth + l * 256 * 128, Wtl + l * 256 * 128,
                                                          bl, br, buf_xl, buf_xr, N_NODES);
        node_attn<<<attn_grid, 256, 0, stream>>>(buf_xl, buf_xr, rowptr, csr_src,
                                                 att, bb, Xh, Xl_);
    }

    pool_head<<<GG / 4, 256, 0, stream>>>(Xh, Xl_, gptr, Wh, bh, out);
}

// Round 7
// 536.044 us; speedup vs baseline: 1.0253x; 1.0253x over previous
//
#include <hip/hip_runtime.h>
#include <hip/hip_fp16.h>
#include <math.h>

#define N_NODES 50000
#define N_EDGES 800000
#define HD 128          // H*D = 4*32
#define GG 1024
#define NEG_SLOPE 0.2f
#define SCAN_B 1024
#define NB ((N_NODES + SCAN_B - 1) / SCAN_B)   // 49

typedef __attribute__((ext_vector_type(8))) short bf16x8;
typedef __attribute__((ext_vector_type(4))) float f32x4;

__device__ __forceinline__ unsigned short f2bf(float v) {
    unsigned u = __float_as_uint(v);
    u += 0x7fff + ((u >> 16) & 1);       // round-to-nearest-even
    return (unsigned short)(u >> 16);
}
__device__ __forceinline__ float bf2f(unsigned short s) {
    return __uint_as_float((unsigned)s << 16);
}
__device__ __forceinline__ void h8_to_f(const uint4& r, float4& v0, float4& v1) {
    const __half2* h = (const __half2*)&r;
    float2 a = __half22float2(h[0]), b = __half22float2(h[1]);
    float2 c = __half22float2(h[2]), d = __half22float2(h[3]);
    v0 = make_float4(a.x, a.y, b.x, b.y);
    v1 = make_float4(c.x, c.y, d.x, d.y);
}

// --------------------------------------------------- split-bf16 conversions
__global__ void convert_x(const float* __restrict__ x, unsigned short* __restrict__ Xh,
                          unsigned short* __restrict__ Xl, int total)
{
    int i = blockIdx.x * 256 + threadIdx.x;
    if (i >= total) return;
    float v = x[i];
    unsigned short hi = f2bf(v);
    unsigned short lo = f2bf(v - bf2f(hi));   // residual exact in fp32
    Xh[i] = hi; Xl[i] = lo;
}

// all 3 layers' W pairs -> Wt[256][K] transposed split hi/lo, one dispatch.
__global__ void convert_w_all(const float* __restrict__ W0l, const float* __restrict__ W0r,
                              const float* __restrict__ W1l, const float* __restrict__ W1r,
                              const float* __restrict__ W2l, const float* __restrict__ W2r,
                              unsigned short* __restrict__ Wth, unsigned short* __restrict__ Wtl)
{
    int t = blockIdx.x * 256 + threadIdx.x;
    if (t >= 256 * 64 + 2 * 256 * 128) return;
    int l, local, K;
    const float* Wl; const float* Wr;
    if (t < 256 * 64)            { l = 0; local = t;              K = 64;  Wl = W0l; Wr = W0r; }
    else if (t < 256 * 64 + 256 * 128) { l = 1; local = t - 256 * 64;  K = 128; Wl = W1l; Wr = W1r; }
    else                         { l = 2; local = t - 256 * 64 - 256 * 128; K = 128; Wl = W2l; Wr = W2r; }
    int c = local / K, k = local - c * K;
    float v = (c < 128) ? Wl[(size_t)k * 128 + c] : Wr[(size_t)k * 128 + (c - 128)];
    unsigned short hi = f2bf(v);
    unsigned short lo = f2bf(v - bf2f(hi));
    Wth[l * 256 * 128 + local] = hi;
    Wtl[l * 256 * 128 + local] = lo;
}

// --------------------------------------------------- MFMA split-bf16 dual GEMM
// NO LDS, NO barriers; register double-buffer over K-chunks.
// Outputs: xl as fp16 (attention gather payload), xr as fp32.
template<int K>
__launch_bounds__(256)
__global__ void gemm_mfma(const unsigned short* __restrict__ Xh, const unsigned short* __restrict__ Xl,
                          const unsigned short* __restrict__ Wth, const unsigned short* __restrict__ Wtl,
                          const float* __restrict__ bl, const float* __restrict__ br,
                          __half* __restrict__ Cl16, float* __restrict__ Cr, int n)
{
    constexpr int NCH = K / 32;
    const int tid  = threadIdx.x;
    const int wave = tid >> 6;
    const int lane = tid & 63;
    const int quad = lane >> 4;
    const int l15  = lane & 15;
    const int row0 = blockIdx.x * 64;

    f32x4 acc[4][4];
    #pragma unroll
    for (int i = 0; i < 4; i++)
        #pragma unroll
        for (int j = 0; j < 4; j++) acc[i][j] = (f32x4){0.f, 0.f, 0.f, 0.f};

    size_t aoff[4];
    #pragma unroll
    for (int mt = 0; mt < 4; mt++) {
        int r = row0 + mt * 16 + l15;
        if (r >= n) r = n - 1;
        aoff[mt] = (size_t)r * K + quad * 8;
    }
    size_t boff[4];
    #pragma unroll
    for (int nt = 0; nt < 4; nt++)
        boff[nt] = (size_t)(wave * 64 + nt * 16 + l15) * K + quad * 8;

    bf16x8 ah[4], al[4], bh[4], bo[4];
    #pragma unroll
    for (int mt = 0; mt < 4; mt++) {
        ah[mt] = *(const bf16x8*)(Xh + aoff[mt]);
        al[mt] = *(const bf16x8*)(Xl + aoff[mt]);
    }
    #pragma unroll
    for (int nt = 0; nt < 4; nt++) {
        bh[nt] = *(const bf16x8*)(Wth + boff[nt]);
        bo[nt] = *(const bf16x8*)(Wtl + boff[nt]);
    }

    #pragma unroll
    for (int ch = 1; ch <= NCH; ch++) {
        bf16x8 nah[4], nal[4], nbh[4], nbo[4];
        if (ch < NCH) {
            const int ko = ch * 32;
            #pragma unroll
            for (int mt = 0; mt < 4; mt++) {
                nah[mt] = *(const bf16x8*)(Xh + aoff[mt] + ko);
                nal[mt] = *(const bf16x8*)(Xl + aoff[mt] + ko);
            }
            #pragma unroll
            for (int nt = 0; nt < 4; nt++) {
                nbh[nt] = *(const bf16x8*)(Wth + boff[nt] + ko);
                nbo[nt] = *(const bf16x8*)(Wtl + boff[nt] + ko);
            }
        }
        #pragma unroll
        for (int nt = 0; nt < 4; nt++) {
            #pragma unroll
            for (int mt = 0; mt < 4; mt++) {
                acc[mt][nt] = __builtin_amdgcn_mfma_f32_16x16x32_bf16(ah[mt], bh[nt], acc[mt][nt], 0, 0, 0);
                acc[mt][nt] = __builtin_amdgcn_mfma_f32_16x16x32_bf16(ah[mt], bo[nt], acc[mt][nt], 0, 0, 0);
                acc[mt][nt] = __builtin_amdgcn_mfma_f32_16x16x32_bf16(al[mt], bh[nt], acc[mt][nt], 0, 0, 0);
            }
        }
        if (ch < NCH) {
            #pragma unroll
            for (int i = 0; i < 4; i++) {
                ah[i] = nah[i]; al[i] = nal[i];
                bh[i] = nbh[i]; bo[i] = nbo[i];
            }
        }
    }

    // epilogue: C/D layout col=lane&15, row=quad*4+reg
    const bool isL = (wave < 2);
    const int colbase = (wave & 1) * 64;
    const float* bias = isL ? bl : br;
    #pragma unroll
    for (int nt = 0; nt < 4; nt++) {
        const int col = colbase + nt * 16 + l15;
        const float bv = bias[col];
        #pragma unroll
        for (int mt = 0; mt < 4; mt++) {
            #pragma unroll
            for (int r = 0; r < 4; r++) {
                const int row = row0 + mt * 16 + quad * 4 + r;
                if (row < n) {
                    const float v = acc[mt][nt][r] + bv;
                    if (isL) Cl16[(size_t)row * 128 + col] = __float2half_rn(v);
                    else     Cr  [(size_t)row * 128 + col] = v;
                }
            }
        }
    }
}

// ---------------------------------------------------------------- CSR build
// edge-degree histogram + graph-boundary build in one dispatch
__global__ void deg_gptr(const int* __restrict__ dst, int* __restrict__ deg,
                         const int* __restrict__ batch, int* __restrict__ gptr)
{
    int i = blockIdx.x * 256 + threadIdx.x;
    if (i < N_EDGES) atomicAdd(&deg[dst[i]], 1);
    if (i <= N_NODES) {
        if (i == 0) {
            for (int g = 0; g <= batch[0]; g++) gptr[g] = 0;
        } else if (i == N_NODES) {
            for (int g = batch[N_NODES - 1] + 1; g <= GG; g++) gptr[g] = N_NODES;
        } else {
            int b0 = batch[i - 1], b1 = batch[i];
            for (int g = b0 + 1; g <= b1; g++) gptr[g] = i;
        }
    }
}

__launch_bounds__(SCAN_B)
__global__ void scan_block(const int* __restrict__ deg, int* __restrict__ rowptr,
                           int* __restrict__ btot)
{
    __shared__ int s[SCAN_B];
    const int tid = threadIdx.x;
    const int i = blockIdx.x * SCAN_B + tid;
    int v = (i < N_NODES) ? deg[i] : 0;
    s[tid] = v;
    __syncthreads();
    for (int off = 1; off < SCAN_B; off <<= 1) {
        int t = (tid >= off) ? s[tid - off] : 0;
        __syncthreads();
        s[tid] += t;
        __syncthreads();
    }
    if (i < N_NODES) rowptr[i] = s[tid] - v;
    if (tid == SCAN_B - 1) btot[blockIdx.x] = s[SCAN_B - 1];
}

// single-wave shfl scan over the NB(=49) block totals
__global__ void scan_btot(const int* __restrict__ btot, int* __restrict__ boff) {
    const int t = threadIdx.x;      // 64 threads
    int v = (t < NB) ? btot[t] : 0;
    const int orig = v;
    #pragma unroll
    for (int off = 1; off < 64; off <<= 1) {
        int u = __shfl_up(v, off);
        if (t >= off) v += u;
    }
    if (t < NB) boff[t] = v - orig;
    if (t == NB - 1) boff[NB] = v;
}

__global__ void scan_add(const int* __restrict__ boff, int* __restrict__ rowptr,
                         int* __restrict__ cursor)
{
    int i = blockIdx.x * 256 + threadIdx.x;
    if (i < N_NODES) {
        int r = rowptr[i] + boff[i >> 10];
        rowptr[i] = r;
        cursor[i] = r;
    }
    if (i == N_NODES) rowptr[N_NODES] = boff[NB];
}

__global__ void scatter_csr(const int* __restrict__ src, const int* __restrict__ dst,
                            int* __restrict__ cursor, int* __restrict__ csr_src)
{
    int e = blockIdx.x * 256 + threadIdx.x;
    if (e >= N_EDGES) return;
    int pos = atomicAdd(&cursor[dst[e]], 1);
    csr_src[pos] = src[e];
}

// ------------------------------------------------- fused per-node attention
// one wave per dst node, FOUR edges in flight (16 lanes x 8 dims each).
// xl gathered as fp16 (16 B/lane); depth-1 pipeline; ballot-gated rescale.
__launch_bounds__(256)
__global__ void node_attn(const __half* __restrict__ xl16, const float* __restrict__ xr,
                          const int* __restrict__ rowptr, const int* __restrict__ csr_src,
                          const float* __restrict__ att, const float* __restrict__ bvec,
                          unsigned short* __restrict__ Hh, unsigned short* __restrict__ Hl)
{
    const int node = (blockIdx.x * 256 + threadIdx.x) >> 6;
    const int lane = threadIdx.x & 63;
    if (node >= N_NODES) return;
    const int eslot = lane >> 4;         // edge slot 0..3
    const int li    = lane & 15;         // dims li*8 .. li*8+7 (head = li>>2)

    const float* xrp = xr + (size_t)node * HD + li * 8;
    const float4 xr0 = *(const float4*)(xrp);
    const float4 xr1 = *(const float4*)(xrp + 4);
    const float4 aw0 = *(const float4*)(att + li * 8);
    const float4 aw1 = *(const float4*)(att + li * 8 + 4);
    const int beg = rowptr[node];
    const int end = rowptr[node + 1];

    float m = -1e30f, l = 0.f;
    float4 a0 = make_float4(0.f, 0.f, 0.f, 0.f);
    float4 a1 = make_float4(0.f, 0.f, 0.f, 0.f);

    int i0 = beg + eslot;
    int s0 = (i0 < end) ? csr_src[i0] : 0;
    uint4 cur = *(const uint4*)(xl16 + (size_t)s0 * HD + li * 8);

    for (int base = beg; base < end; base += 4) {
        const bool valid = (base + eslot) < end;
        uint4 nxt = cur;
        if (base + 4 < end) {
            int e2 = base + 4 + eslot;
            int s2 = (e2 < end) ? csr_src[e2] : 0;
            nxt = *(const uint4*)(xl16 + (size_t)s2 * HD + li * 8);
        }
        float4 v0, v1;
        h8_to_f(cur, v0, v1);
        // score partial over this lane's 8 dims: leaky = max(t, 0.2t)
        float t, p;
        t = v0.x + xr0.x; t = fmaxf(t, NEG_SLOPE * t); p  = t * aw0.x;
        t = v0.y + xr0.y; t = fmaxf(t, NEG_SLOPE * t); p += t * aw0.y;
        t = v0.z + xr0.z; t = fmaxf(t, NEG_SLOPE * t); p += t * aw0.z;
        t = v0.w + xr0.w; t = fmaxf(t, NEG_SLOPE * t); p += t * aw0.w;
        t = v1.x + xr1.x; t = fmaxf(t, NEG_SLOPE * t); p += t * aw1.x;
        t = v1.y + xr1.y; t = fmaxf(t, NEG_SLOPE * t); p += t * aw1.y;
        t = v1.z + xr1.z; t = fmaxf(t, NEG_SLOPE * t); p += t * aw1.z;
        t = v1.w + xr1.w; t = fmaxf(t, NEG_SLOPE * t); p += t * aw1.w;
        p += __shfl_xor(p, 1);
        p += __shfl_xor(p, 2);           // head score replicated in 4-lane group

        if (!__any(valid && (p > m))) {  // fast path: no head's max improves
            const float w = valid ? __expf(p - m) : 0.f;
            l += w;
            a0.x += w * v0.x; a0.y += w * v0.y; a0.z += w * v0.z; a0.w += w * v0.w;
            a1.x += w * v1.x; a1.y += w * v1.y; a1.z += w * v1.z; a1.w += w * v1.w;
        } else {
            const float mn = valid ? fmaxf(m, p) : m;
            const float sc = __expf(m - mn);
            const float w  = valid ? __expf(p - mn) : 0.f;
            l = l * sc + w;
            a0.x = a0.x * sc + w * v0.x; a0.y = a0.y * sc + w * v0.y;
            a0.z = a0.z * sc + w * v0.z; a0.w = a0.w * sc + w * v0.w;
            a1.x = a1.x * sc + w * v1.x; a1.y = a1.y * sc + w * v1.y;
            a1.z = a1.z * sc + w * v1.z; a1.w = a1.w * sc + w * v1.w;
            m = mn;
        }
        cur = nxt;
    }

    // merge the 4 edge-slot softmax states (xor 16, then xor 32)
    #pragma unroll
    for (int off = 16; off <= 32; off <<= 1) {
        const float mo = __shfl_xor(m, off);
        const float lo = __shfl_xor(l, off);
        float4 b0, b1;
        b0.x = __shfl_xor(a0.x, off); b0.y = __shfl_xor(a0.y, off);
        b0.z = __shfl_xor(a0.z, off); b0.w = __shfl_xor(a0.w, off);
        b1.x = __shfl_xor(a1.x, off); b1.y = __shfl_xor(a1.y, off);
        b1.z = __shfl_xor(a1.z, off); b1.w = __shfl_xor(a1.w, off);
        const float mm = fmaxf(m, mo);
        const float e1 = __expf(m - mm);
        const float e2 = __expf(mo - mm);
        l = l * e1 + lo * e2;
        a0.x = a0.x * e1 + b0.x * e2; a0.y = a0.y * e1 + b0.y * e2;
        a0.z = a0.z * e1 + b0.z * e2; a0.w = a0.w * e1 + b0.w * e2;
        a1.x = a1.x * e1 + b1.x * e2; a1.y = a1.y * e1 + b1.y * e2;
        a1.z = a1.z * e1 + b1.z * e2; a1.w = a1.w * e1 + b1.w * e2;
        m = mm;
    }

    if (eslot == 0) {
        const float inv = (l > 0.f) ? 1.f / l : 0.f;
        const float4 bb0 = *(const float4*)(bvec + li * 8);
        const float4 bb1 = *(const float4*)(bvec + li * 8 + 4);
        float o[8];
        o[0] = a0.x * inv + bb0.x; o[1] = a0.y * inv + bb0.y;
        o[2] = a0.z * inv + bb0.z; o[3] = a0.w * inv + bb0.w;
        o[4] = a1.x * inv + bb1.x; o[5] = a1.y * inv + bb1.y;
        o[6] = a1.z * inv + bb1.z; o[7] = a1.w * inv + bb1.w;
        uint4 ph, pl;
        unsigned* php = (unsigned*)&ph;
        unsigned* plp = (unsigned*)&pl;
        #pragma unroll
        for (int j = 0; j < 4; j++) {
            float u0 = o[2*j], u1 = o[2*j+1];
            u0 = (u0 > 0.f) ? u0 : expm1f(u0);
            u1 = (u1 > 0.f) ? u1 : expm1f(u1);
            unsigned short h0 = f2bf(u0), h1 = f2bf(u1);
            unsigned short q0 = f2bf(u0 - bf2f(h0)), q1 = f2bf(u1 - bf2f(h1));
            php[j] = (unsigned)h0 | ((unsigned)h1 << 16);
            plp[j] = (unsigned)q0 | ((unsigned)q1 << 16);
        }
        *(uint4*)(Hh + (size_t)node * HD + li * 8) = ph;
        *(uint4*)(Hl + (size_t)node * HD + li * 8) = pl;
    }
}

// ------------------------------------------ fused mean-pool + linear head
__launch_bounds__(256)
__global__ void pool_head(const unsigned short* __restrict__ Hh, const unsigned short* __restrict__ Hl,
                          const int* __restrict__ gptr, const float* __restrict__ Wh,
                          const float* __restrict__ bh, float* __restrict__ out)
{
    const int g = (blockIdx.x * 256 + threadIdx.x) >> 6;
    const int lane = threadIdx.x & 63;
    if (g >= GG) return;
    const int b0 = gptr[g], b1 = gptr[g + 1];
    const float2 w = *(const float2*)(Wh + lane * 2);
    float sx = 0.f, sy = 0.f;
    for (int i = b0; i < b1; i++) {
        const unsigned vh = *(const unsigned*)(Hh + (size_t)i * HD + lane * 2);
        const unsigned vl = *(const unsigned*)(Hl + (size_t)i * HD + lane * 2);
        sx += bf2f((unsigned short)(vh & 0xffff)) + bf2f((unsigned short)(vl & 0xffff));
        sy += bf2f((unsigned short)(vh >> 16))    + bf2f((unsigned short)(vl >> 16));
    }
    float d = sx * w.x + sy * w.y;
    d += __shfl_xor(d, 1);
    d += __shfl_xor(d, 2);
    d += __shfl_xor(d, 4);
    d += __shfl_xor(d, 8);
    d += __shfl_xor(d, 16);
    d += __shfl_xor(d, 32);
    if (lane == 0) out[g] = d / fmaxf((float)(b1 - b0), 1.f) + bh[0];
}

// ---------------------------------------------------------------- launch
extern "C" void kernel_launch(void* const* d_in, const int* in_sizes, int n_in,
                              void* d_out, int out_size, void* d_ws, size_t ws_size,
                              hipStream_t stream)
{
    const float* x     = (const float*)d_in[0];
    const int*   edge  = (const int*)d_in[1];
    const int*   batch = (const int*)d_in[2];
    const int*   src   = edge;
    const int*   dst   = edge + N_EDGES;
    const float* Wh    = (const float*)d_in[21];
    const float* bh    = (const float*)d_in[22];
    float* out = (float*)d_out;

    const size_t N128 = (size_t)N_NODES * HD;
    __half* xl16  = (__half*)d_ws;                      // N*128 fp16
    float* buf_xr = (float*)(xl16 + N128);              // N*128 f32
    unsigned short* Xh  = (unsigned short*)(buf_xr + N128);   // N*128 bf16
    unsigned short* Xl_ = Xh + N128;                    // N*128 bf16
    unsigned short* Wth = Xl_ + N128;                   // 3 * 256*128 bf16
    unsigned short* Wtl = Wth + 3 * 256 * 128;          // 3 * 256*128 bf16
    int* deg     = (int*)(Wtl + 3 * 256 * 128);         // N
    int* rowptr  = deg + N_NODES;                       // N+1
    int* cursor  = rowptr + N_NODES + 1;                // N
    int* csr_src = cursor + N_NODES;                    // E
    int* btot    = csr_src + N_EDGES;                   // NB
    int* boff    = btot + NB;                           // NB+1
    int* gptr    = boff + NB + 1;                       // G+1

    // ---- CSR + graph-boundary build (layer-invariant)
    hipMemsetAsync(deg, 0, (size_t)N_NODES * sizeof(int), stream);
    deg_gptr<<<(N_EDGES + 255) / 256, 256, 0, stream>>>(dst, deg, batch, gptr);
    scan_block<<<NB, SCAN_B, 0, stream>>>(deg, rowptr, btot);
    scan_btot<<<1, 64, 0, stream>>>(btot, boff);
    scan_add<<<(N_NODES + 256) / 256, 256, 0, stream>>>(boff, rowptr, cursor);
    scatter_csr<<<(N_EDGES + 255) / 256, 256, 0, stream>>>(src, dst, cursor, csr_src);

    // ---- weight + layer-0 input split-bf16 conversion
    convert_x<<<(N_NODES * 64 + 255) / 256, 256, 0, stream>>>(x, Xh, Xl_, N_NODES * 64);
    convert_w_all<<<(256 * 64 + 2 * 256 * 128 + 255) / 256, 256, 0, stream>>>(
        (const float*)d_in[3],  (const float*)d_in[5],
        (const float*)d_in[9],  (const float*)d_in[11],
        (const float*)d_in[15], (const float*)d_in[17], Wth, Wtl);

    const int gemm_grid = (N_NODES + 63) / 64;
    const int attn_grid = (N_NODES + 3) / 4;

    for (int l = 0; l < 3; l++) {
        const float* bl  = (const float*)d_in[4 + 6 * l];
        const float* br  = (const float*)d_in[6 + 6 * l];
        const float* att = (const float*)d_in[7 + 6 * l];
        const float* bb  = (const float*)d_in[8 + 6 * l];

        if (l == 0)
            gemm_mfma<64><<<gemm_grid, 256, 0, stream>>>(Xh, Xl_, Wth, Wtl,
                                                         bl, br, xl16, buf_xr, N_NODES);
        else
            gemm_mfma<128><<<gemm_grid, 256, 0, stream>>>(Xh, Xl_,
                                                          Wth + l * 256 * 128, Wtl + l * 256 * 128,
                                                          bl, br, xl16, buf_xr, N_NODES);
        node_attn<<<attn_grid, 256, 0, stream>>>(xl16, buf_xr, rowptr, csr_src,
                                                 att, bb, Xh, Xl_);
    }

    pool_head<<<GG / 4, 256, 0, stream>>>(Xh, Xl_, gptr, Wh, bh, out);
}